// Round 1
// baseline (72.581 us; speedup 1.0000x reference)
//
#include <hip/hip_runtime.h>
#include <math.h>

#define B 2
#define S 1024
#define H 1024
#define NIN 512
#define NP 32
#define SC 16            // s-chunks for context partials
#define SCHUNK (S / SC)  // 64

// ---------- K0: normalize templates [32][512] ----------
__global__ void k_tmpl_norm(const float* __restrict__ tmpl, float* __restrict__ tn) {
    int n = blockIdx.x;        // 0..31
    int lane = threadIdx.x;    // 0..63
    const float* row = tmpl + (size_t)n * NIN;
    float v[8];
    float ss = 0.f;
#pragma unroll
    for (int k = 0; k < 8; ++k) { v[k] = row[lane + 64 * k]; ss += v[k] * v[k]; }
#pragma unroll
    for (int off = 32; off; off >>= 1) ss += __shfl_down(ss, off);
    ss = __shfl(ss, 0);
    float inv = 1.f / fmaxf(sqrtf(ss), 1e-12f);
#pragma unroll
    for (int k = 0; k < 8; ++k) tn[(size_t)n * NIN + lane + 64 * k] = v[k] * inv;
}

// ---------- K1: P[b,s,n] = sigmoid(act_norm . tmpl_norm) ----------
// block = 256 threads = 8 tokens x 32 templates
__global__ void k_pattern(const float* __restrict__ act, const float* __restrict__ tn,
                          float* __restrict__ P) {
    __shared__ float act_lds[8][NIN];   // 16 KB
    int tid = threadIdx.x;
    int t0 = blockIdx.x * 8;
    {
        const float* src = act + (size_t)t0 * NIN;
        float* dst = &act_lds[0][0];
        for (int k = tid; k < 8 * NIN; k += 256) dst[k] = src[k];
    }
    __syncthreads();
    int tok = tid >> 5;   // 0..7
    int n   = tid & 31;   // 0..31
    // sumsq of this token's row (32 lanes cooperate)
    float ss = 0.f;
#pragma unroll
    for (int k = 0; k < 16; ++k) { float x = act_lds[tok][n + 32 * k]; ss += x * x; }
#pragma unroll
    for (int m = 16; m; m >>= 1) ss += __shfl_xor(ss, m);
    float inv = 1.f / fmaxf(sqrtf(ss), 1e-12f);
    // dot with template n (float4)
    const float4* t4 = (const float4*)(tn + (size_t)n * NIN);
    const float4* a4 = (const float4*)(&act_lds[tok][0]);
    float d = 0.f;
#pragma unroll 8
    for (int i = 0; i < NIN / 4; ++i) {
        float4 tv = t4[i];
        float4 av = a4[i];
        d += tv.x * av.x + tv.y * av.y + tv.z * av.z + tv.w * av.w;
    }
    d *= inv;
    float p = 1.f / (1.f + expf(-d));
    P[(size_t)(t0 + tok) * NP + n] = p;
}

// ---------- K1b: norm[b,n] = sum_s P[b,s,n] + 1e-8 ----------
__global__ void k_norm(const float* __restrict__ P, float* __restrict__ nrm) {
    int bn = blockIdx.x;       // 0..63
    int b = bn >> 5, n = bn & 31;
    int tid = threadIdx.x;     // 256
    float s = 0.f;
#pragma unroll
    for (int k = 0; k < 4; ++k) {
        int si = tid + 256 * k;
        s += P[((size_t)b * S + si) * NP + n];
    }
    __shared__ float red[256];
    red[tid] = s;
    __syncthreads();
    for (int off = 128; off >= 1; off >>= 1) {
        if (tid < off) red[tid] += red[tid + off];
        __syncthreads();
    }
    if (tid == 0) nrm[bn] = red[0] + 1e-8f;
}

// ---------- K2: partial contexts over s-chunks ----------
// grid = B * SC * 8 (h-tiles of 128); block 256 = 128 h x 2 n-groups of 16
__global__ void k_ctx_partial(const float* __restrict__ I, const float* __restrict__ P,
                              float* __restrict__ part) {
    int bid = blockIdx.x;
    int ht = bid & 7;
    int sc = (bid >> 3) & (SC - 1);
    int b  = bid >> 7;
    int tid = threadIdx.x;
    __shared__ float Pl[SCHUNK][NP];   // 8 KB
    int s0 = sc * SCHUNK;
    {
        const float* src = P + ((size_t)b * S + s0) * NP;
        float* dst = &Pl[0][0];
        for (int k = tid; k < SCHUNK * NP; k += 256) dst[k] = src[k];
    }
    __syncthreads();
    int hl = tid & 127;
    int g  = tid >> 7;                 // 0/1 -> n in [16g, 16g+16)
    int h  = ht * 128 + hl;
    float acc[16];
#pragma unroll
    for (int j = 0; j < 16; ++j) acc[j] = 0.f;
    const float* Ip = I + ((size_t)b * S + s0) * H + h;
    for (int s = 0; s < SCHUNK; ++s) {
        float x = Ip[(size_t)s * H];
#pragma unroll
        for (int j = 0; j < 16; ++j) acc[j] += x * Pl[s][g * 16 + j];
    }
    size_t base = (((size_t)b * SC + sc) * NP + g * 16) * H + h;
#pragma unroll
    for (int j = 0; j < 16; ++j) part[base + (size_t)j * H] = acc[j];
}

// ---------- K3: reduce partials, divide by norm ----------
__global__ void k_ctx_reduce(const float* __restrict__ part, const float* __restrict__ nrm,
                             float* __restrict__ ctx) {
    int idx = blockIdx.x * 256 + threadIdx.x;    // 0 .. B*NP*H-1
    int n = (idx >> 10) & 31;
    int b = idx >> 15;
    float s = 0.f;
#pragma unroll
    for (int sc = 0; sc < SC; ++sc)
        s += part[((size_t)(b * SC + sc) * NP + n) * H + (idx & 1023)];
    ctx[idx] = s / nrm[b * NP + n];
}

// ---------- K4: transformed[b,n,k] = sum_h ctx[b,n,h] * W[n,k,h] ----------
// grid = 32 * 256 blocks; block 256 = 4 waves, 1 W-row per wave, both batches
__global__ void k_transform(const float* __restrict__ W, const float* __restrict__ ctx,
                            float* __restrict__ T) {
    int bid = blockIdx.x;
    int n  = bid >> 8;     // 0..31
    int kg = bid & 255;    // k-group of 4
    __shared__ float cl[2 * H];   // 8 KB
    int tid = threadIdx.x;
    for (int k = tid; k < 2 * H; k += 256) {
        int b = k >> 10, h = k & 1023;
        cl[k] = ctx[((size_t)b * NP + n) * H + h];
    }
    __syncthreads();
    int w = tid >> 6;
    int lane = tid & 63;
    int kk = kg * 4 + w;
    const float4* Wr = (const float4*)(W + ((size_t)n * H + kk) * H);
    const float4* c0 = (const float4*)(cl);
    const float4* c1 = (const float4*)(cl + H);
    float a0 = 0.f, a1 = 0.f;
#pragma unroll
    for (int it = 0; it < 4; ++it) {
        int idx = it * 64 + lane;
        float4 wv = Wr[idx];
        float4 v0 = c0[idx];
        float4 v1 = c1[idx];
        a0 += wv.x * v0.x + wv.y * v0.y + wv.z * v0.z + wv.w * v0.w;
        a1 += wv.x * v1.x + wv.y * v1.y + wv.z * v1.z + wv.w * v1.w;
    }
#pragma unroll
    for (int off = 32; off; off >>= 1) {
        a0 += __shfl_down(a0, off);
        a1 += __shfl_down(a1, off);
    }
    if (lane == 0) {
        T[(size_t)n * H + kk] = a0;
        T[((size_t)NP + n) * H + kk] = a1;
    }
}

// ---------- K5: combined[b,s,h] = sum_n T[b,n,h] * P[b,s,n] ----------
// grid = B * (S/16) * (H/256); block 256, thread owns one h
__global__ void k_combine(const float* __restrict__ T, const float* __restrict__ P,
                          float* __restrict__ out) {
    int bid = blockIdx.x;
    int ht = bid & 3;
    int sc = (bid >> 2) & 63;
    int b  = bid >> 8;
    int tid = threadIdx.x;
    __shared__ float Tl[NP][256];   // 32 KB
    __shared__ float Pl[16][NP];    // 2 KB
    int h0 = ht * 256;
    for (int k = tid; k < NP * 256; k += 256) {
        int n = k >> 8, h = k & 255;
        Tl[n][h] = T[((size_t)b * NP + n) * H + h0 + h];
    }
    int s0 = sc * 16;
    {
        const float* src = P + ((size_t)b * S + s0) * NP;
        float* dst = &Pl[0][0];
        for (int k = tid; k < 16 * NP; k += 256) dst[k] = src[k];
    }
    __syncthreads();
    for (int s = 0; s < 16; ++s) {
        float acc = 0.f;
#pragma unroll
        for (int n = 0; n < NP; ++n) acc += Pl[s][n] * Tl[n][tid];
        out[((size_t)b * S + s0 + s) * H + h0 + tid] = acc;
    }
}

extern "C" void kernel_launch(void* const* d_in, const int* in_sizes, int n_in,
                              void* d_out, int out_size, void* d_ws, size_t ws_size,
                              hipStream_t stream) {
    const float* I    = (const float*)d_in[0];  // [B,S,H]
    const float* act  = (const float*)d_in[1];  // [B,S,NIN]
    const float* tmpl = (const float*)d_in[2];  // [NP,NIN]
    const float* W    = (const float*)d_in[3];  // [NP*H,H]
    float* out  = (float*)d_out;                // combined [B,S,H]
    float* Pout = out + (size_t)B * S * H;      // process_activations [B,S,NP]

    float* ws   = (float*)d_ws;
    float* tn   = ws;                                   // 32*512
    float* nrm  = tn + (size_t)NP * NIN;                // 64
    float* part = nrm + 64;                             // B*SC*NP*H
    float* ctx  = part + (size_t)B * SC * NP * H;       // B*NP*H
    float* T    = ctx + (size_t)B * NP * H;             // B*NP*H

    k_tmpl_norm  <<<NP,                 64, 0, stream>>>(tmpl, tn);
    k_pattern    <<<B * S / 8,         256, 0, stream>>>(act, tn, Pout);
    k_norm       <<<B * NP,            256, 0, stream>>>(Pout, nrm);
    k_ctx_partial<<<B * SC * 8,        256, 0, stream>>>(I, Pout, part);
    k_ctx_reduce <<<B * NP * H / 256,  256, 0, stream>>>(part, nrm, ctx);
    k_transform  <<<NP * 256,          256, 0, stream>>>(W, ctx, T);
    k_combine    <<<B * (S/16) * (H/256), 256, 0, stream>>>(T, Pout, out);
}